// Round 11
// baseline (399.741 us; speedup 1.0000x reference)
//
#include <hip/hip_runtime.h>
#include <hip/hip_bf16.h>
#include <hip/hip_fp16.h>
#include <stdint.h>

// B=16, N=2048, D=512. Inputs/outputs FLOAT32; internal bf16/fp16.
// Algebra: S = x(WqWk^T)x^T ; out*N = (c^T x)Wv  -> q,k,v never materialized.
// Ladder: r2=348.8 | r4 LDS-epi REF | r5 T1 REF | r6 recompute REF | r7 NT
// REF | r8=313.8 | r9 persistent(block-linear) REF (FETCH 2x — cohort
// locality destroyed) | r10=312.5 (merged cast). This round: persistent with
// STRIDE-interleaved tile map (tile = bid + 256*ti) — preserves r10's
// 4-batch/16MB L2-resident cohorts while amortizing prologue fills and
// overlapping epilogue stores with next-tile compute.
#define NB 16
#define NN 2048
#define ND 512
#define SSCALE 0.044194173824159216f        // 1/sqrt(512)

typedef unsigned short u16;
typedef unsigned int u32;
typedef float f32x4 __attribute__((ext_vector_type(4)));
typedef __bf16 bf16x8 __attribute__((ext_vector_type(8)));
typedef unsigned short u16x8 __attribute__((ext_vector_type(8)));

__device__ __forceinline__ float bf2f(u16 h) {
  union { u32 u; float f; } v; v.u = ((u32)h) << 16; return v.f;
}
__device__ __forceinline__ u16 f2bf(float f) {
  union { float f; u32 u; } v; v.f = f;
  u32 r = v.u + 0x7fffu + ((v.u >> 16) & 1u);   // RNE
  return (u16)(r >> 16);
}
__device__ __forceinline__ u16 f2h(float f) {
  __half h = __float2half(f);
  union { __half h; u16 u; } v; v.h = h; return v.u;
}
__device__ __forceinline__ float h2f(u16 u) {
  union { u16 u; __half h; } v; v.u = u; return __half2float(v.h);
}

// async global->LDS, 16B/lane (wave-uniform base + lane*16 contract).
__device__ __forceinline__ void async16(const void* g, void* l) {
  __builtin_amdgcn_global_load_lds(
      (const __attribute__((address_space(1))) u32*)g,
      (__attribute__((address_space(3))) u32*)l,
      16, 0, 0);
}

// ===========================================================================
// OLD 128x128 kernel (m97 structure) — kept for the tiny Mt GEMM (AF32 path)
// and the small-workspace fallback.
// ===========================================================================
template <int MODE, bool AF32>
__global__ __launch_bounds__(256, 2) void gemm_bt(
    const void* __restrict__ Av, const u16* __restrict__ B, u16* __restrict__ C,
    float* __restrict__ Lrow, int lda, int ldb, int ldc, int K,
    long long sA, long long sB, long long sC, float cscale) {
  const int tid  = threadIdx.x;
  const int w    = tid >> 6;
  const int lane = tid & 63;
  const int wm   = w >> 1, wn = w & 1;
  const int lrow = lane & 15, quad = lane >> 4;
  const long long z = blockIdx.z;

  const float* Abf = (const float*)Av + z * sA + (size_t)blockIdx.y * 128 * lda;
  const u16*   Abh = (const u16*)Av   + z * sA + (size_t)blockIdx.y * 128 * lda;
  const u16*   Bb  = B + z * sB + (size_t)blockIdx.x * 128 * ldb;

  __shared__ __align__(16) u16 lds_a[128 * 32];
  __shared__ __align__(16) u16 lds_b[128 * 32];

  f32x4 acc[4][4];
#pragma unroll
  for (int i = 0; i < 4; i++)
#pragma unroll
    for (int j = 0; j < 4; j++) acc[i][j] = (f32x4){0.f, 0.f, 0.f, 0.f};

  for (int k0 = 0; k0 < K; k0 += 32) {
    if (k0) __syncthreads();
    if (AF32) {
      u16x8 va[2];
#pragma unroll
      for (int t = 0; t < 2; t++) {
        int ch  = t * 256 + tid;
        int row = ch >> 2;
        int cc  = (ch & 3) * 8;
        const float4* p = (const float4*)(Abf + (size_t)row * lda + k0 + cc);
        float4 f0 = p[0], f1 = p[1];
        u16x8 r;
        r[0] = f2bf(f0.x); r[1] = f2bf(f0.y); r[2] = f2bf(f0.z); r[3] = f2bf(f0.w);
        r[4] = f2bf(f1.x); r[5] = f2bf(f1.y); r[6] = f2bf(f1.z); r[7] = f2bf(f1.w);
        va[t] = r;
        async16(Bb + (size_t)row * ldb + k0 + cc, &lds_b[ch * 8]);
      }
#pragma unroll
      for (int t = 0; t < 2; t++) *(u16x8*)&lds_a[(t * 256 + tid) * 8] = va[t];
    } else {
#pragma unroll
      for (int t = 0; t < 2; t++) {
        int ch  = t * 256 + tid;
        int row = ch >> 2;
        int cc  = (ch & 3) * 8;
        async16(Abh + (size_t)row * lda + k0 + cc, &lds_a[ch * 8]);
        async16(Bb  + (size_t)row * ldb + k0 + cc, &lds_b[ch * 8]);
      }
    }
    __syncthreads();

    bf16x8 af[4], bfr[4];
#pragma unroll
    for (int i = 0; i < 4; i++) {
      af[i]  = *(const bf16x8*)&lds_a[(wm * 64 + i * 16 + lrow) * 32 + quad * 8];
      bfr[i] = *(const bf16x8*)&lds_b[(wn * 64 + i * 16 + lrow) * 32 + quad * 8];
    }
#pragma unroll
    for (int i = 0; i < 4; i++)
#pragma unroll
      for (int j = 0; j < 4; j++)
        acc[i][j] =
            __builtin_amdgcn_mfma_f32_16x16x32_bf16(af[i], bfr[j], acc[i][j], 0, 0, 0);
  }

  u16* Cb = C + z * sC + (size_t)blockIdx.y * 128 * ldc + (size_t)blockIdx.x * 128;
  if (MODE == 0) {
#pragma unroll
    for (int i = 0; i < 4; i++)
#pragma unroll
      for (int j = 0; j < 4; j++)
#pragma unroll
        for (int r = 0; r < 4; r++) {
          int row = wm * 64 + i * 16 + quad * 4 + r;
          int col = wn * 64 + j * 16 + lrow;
          Cb[(size_t)row * ldc + col] = f2bf(acc[i][j][r] * cscale);
        }
  } else {
    float* Lb = Lrow + z * NN + (size_t)blockIdx.y * 128;
#pragma unroll
    for (int i = 0; i < 4; i++)
#pragma unroll
      for (int r = 0; r < 4; r++) {
        int row = wm * 64 + i * 16 + quad * 4 + r;
        float rs = 0.f;
#pragma unroll
        for (int j = 0; j < 4; j++) {
          int col = wn * 64 + j * 16 + lrow;
          float e = __expf(fminf(acc[i][j][r] * cscale, 10.f));
          Cb[(size_t)row * ldc + col] = f2h(e);
          rs += e;
        }
        rs += __shfl_xor(rs, 1); rs += __shfl_xor(rs, 2);
        rs += __shfl_xor(rs, 4); rs += __shfl_xor(rs, 8);
        if (lrow == 0) atomicAdd(&Lb[row], rs);
      }
  }
}

// ===========================================================================
// 256x256 8-phase GEMM (T2 swizzle + T3/T4 counted vmcnt + T5 setprio),
// PERSISTENT with STRIDE-interleaved tile map: block bid processes tiles
// {bid + stride*ti : ti<tpb}. At step ti all `stride` resident blocks work
// the SAME z-cohort (r10's dispatcher generations) -> panels stay
// L2-resident (r9's bid*tpb+ti map doubled FETCH — refuted). Cross-tile
// staging keeps the pipeline full at tile boundaries; epilogue stores
// overlap the next tile's compute (their vmcnt inflation only makes later
// vmcnt(4) checks stricter -> correct by construction).
// MODE 0: store bf16(C*cscale). MODE 1: store fp16(exp(min(C,10))) + row
// expsum atomicAdd into Lrow.
// ===========================================================================
__device__ __forceinline__ void stage_half(const u16* __restrict__ g, int ld,
                                           int row0, int k0,
                                           u16* __restrict__ l, int tid) {
  int r  = tid >> 3;                    // 0..63
  int Lc = (tid & 7) ^ (r & 7);         // inverse-swizzled source chunk
  async16(g + (size_t)(row0 + r) * ld + k0 + Lc * 8, l + tid * 8);
  async16(g + (size_t)(row0 + 64 + r) * ld + k0 + Lc * 8, l + 4096 + tid * 8);
}

__device__ __forceinline__ bf16x8 ldf(const u16* __restrict__ h, int rbase,
                                      int lrow, int quad, int ks) {
  int rr = rbase + lrow;
  int pc = (ks * 4 + quad) ^ (lrow & 7);  // swizzled read chunk
  return *(const bf16x8*)&h[rr * 64 + pc * 8];
}

#define BAR() __builtin_amdgcn_s_barrier()
#define WAIT_LGKM()                                          \
  do {                                                       \
    asm volatile("s_waitcnt lgkmcnt(0)" ::: "memory");       \
    __builtin_amdgcn_sched_barrier(0);                       \
  } while (0)

#define READ_A(p, mh)                                                        \
  _Pragma("unroll") for (int i2 = 0; i2 < 4; ++i2)                           \
  _Pragma("unroll") for (int ks = 0; ks < 2; ++ks)                           \
      af[i2][ks] = ldf(sm + (p) * 32768 + wm * 8192, ((mh)*4 + i2) * 16,     \
                       lrow, quad, ks);

#define READ_B(p, nh)                                                        \
  _Pragma("unroll") for (int j2 = 0; j2 < 2; ++j2)                           \
  _Pragma("unroll") for (int ks = 0; ks < 2; ++ks)                           \
      bq[(nh)*2 + j2][ks] =                                                  \
          ldf(sm + (p) * 32768 + 16384 + (wn >> 1) * 8192,                   \
              (wn & 1) * 64 + ((nh)*2 + j2) * 16, lrow, quad, ks);

#define MFMA_Q(mh, nh)                                                       \
  __builtin_amdgcn_s_setprio(1);                                             \
  _Pragma("unroll") for (int i2 = 0; i2 < 4; ++i2)                           \
  _Pragma("unroll") for (int j2 = 0; j2 < 2; ++j2)                           \
  _Pragma("unroll") for (int ks = 0; ks < 2; ++ks)                           \
      acc[(mh)*4 + i2][(nh)*2 + j2] = __builtin_amdgcn_mfma_f32_16x16x32_bf16( \
          af[i2][ks], bq[(nh)*2 + j2][ks], acc[(mh)*4 + i2][(nh)*2 + j2],    \
          0, 0, 0);                                                          \
  __builtin_amdgcn_s_setprio(0);

#define STAGE_A(p, base, h, kt) \
  stage_half(base, lda, (h)*128, (kt)*64, sm + (p)*32768 + (h)*8192, tid)
#define STAGE_B(p, base, h, kt) \
  stage_half(base, ldb, (h)*128, (kt)*64, sm + (p)*32768 + 16384 + (h)*8192, tid)

template <int MODE>
__global__ __launch_bounds__(512, 2) void gemm256(
    const u16* __restrict__ A, const u16* __restrict__ B, u16* __restrict__ C,
    float* __restrict__ Lrow, int lda, int ldb, int ldc,
    int tpb, int stride, int tgxs, int tgys,
    long long sA, long long sB, long long sC, float cscale) {
  const int tid  = threadIdx.x;
  const int wid  = tid >> 6, lane = tid & 63;
  const int wm   = wid >> 2, wn = wid & 3;   // 2 M-waves x 4 N-waves
  const int lrow = lane & 15, quad = lane >> 4;

  __shared__ __align__(16) u16 sm[65536];   // 128 KiB

  f32x4 acc[8][4];
#pragma unroll
  for (int i = 0; i < 8; i++)
#pragma unroll
    for (int j = 0; j < 4; j++) acc[i][j] = (f32x4){0.f, 0.f, 0.f, 0.f};

  bf16x8 af[4][2];
  bf16x8 bq[4][2];

  const int gmask = (1 << tgxs) - 1;
  const int tmask = (1 << (tgxs + tgys)) - 1;

  // ---- decode first tile (ot = bid)
  int bxxC, byyC; long long zC;
  const u16 *AbC, *BbC;
  {
    int ot = blockIdx.x;
    zC = (long long)(ot >> (tgxs + tgys));
    int rem = ot & tmask;
    byyC = rem >> tgxs; bxxC = rem & gmask;
    AbC = A + zC * sA + (size_t)byyC * 256 * lda;
    BbC = B + zC * sB + (size_t)bxxC * 256 * ldb;
  }

  // ---- prologue: A0(0), B0(0), B1(1) of first tile
  STAGE_A(0, AbC, 0, 0); STAGE_A(0, AbC, 1, 0);
  STAGE_B(0, BbC, 0, 0); STAGE_B(0, BbC, 1, 0);
  STAGE_B(1, BbC, 0, 1); STAGE_B(1, BbC, 1, 1);
  asm volatile("s_waitcnt vmcnt(4)" ::: "memory");
  __builtin_amdgcn_sched_barrier(0);
  BAR();

  for (int ti = 0; ti < tpb; ++ti) {
    const bool lastTile = (ti + 1 == tpb);
    // ---- decode next tile (cross-tile stage targets): ot = bid+stride*(ti+1)
    int bxxN = bxxC, byyN = byyC; long long zN = zC;
    const u16 *AbN = AbC, *BbN = BbC;
    if (!lastTile) {
      int ot = blockIdx.x + stride * (ti + 1);
      zN = (long long)(ot >> (tgxs + tgys));
      int rem = ot & tmask;
      byyN = rem >> tgxs; bxxN = rem & gmask;
      AbN = A + zN * sA + (size_t)byyN * 256 * lda;
      BbN = B + zN * sB + (size_t)bxxN * 256 * ldb;
    }

    for (int it = 0; it < 4; ++it) {
      const int t = 2 * it;
      const bool lastIt = (it == 3);
      const bool more = !(lastIt && lastTile);
      const u16* Ax = lastIt ? AbN : AbC;   // t+2 crosses only at it=3
      const u16* Bx = lastIt ? BbN : BbC;
      const int k2 = (t + 2) & 7, k3 = (t + 3) & 7;

      // -- g1: kt-pair t (p0), quadrant (mh0,nh0); stage A1(t+1)h0
      READ_A(0, 0); READ_B(0, 0);
      STAGE_A(1, AbC, 0, t + 1);
      BAR(); WAIT_LGKM();
      MFMA_Q(0, 0);
      BAR();
      // -- g2: (mh0,nh1); stage A1(t+1)h1
      READ_B(0, 1);
      STAGE_A(1, AbC, 1, t + 1);
      BAR(); WAIT_LGKM();
      MFMA_Q(0, 1);
      BAR();
      // -- g3: (mh1,nh0); stage B0(k2)h0
      READ_A(0, 1);
      if (more) STAGE_B(0, Bx, 0, k2);
      BAR(); WAIT_LGKM();
      MFMA_Q(1, 0);
      BAR();
      // -- g4: (mh1,nh1); stage B0(k2)h1; counted vmcnt
      if (more) STAGE_B(0, Bx, 1, k2);
      BAR();
      MFMA_Q(1, 1);
      if (more) { asm volatile("s_waitcnt vmcnt(4)" ::: "memory"); }
      else      { asm volatile("s_waitcnt vmcnt(0)" ::: "memory"); }
      __builtin_amdgcn_sched_barrier(0);
      BAR();
      // -- g5: pair t+1 (p1), (mh0,nh0); stage A0(k2)h0
      READ_A(1, 0); READ_B(1, 0);
      if (more) STAGE_A(0, Ax, 0, k2);
      BAR(); WAIT_LGKM();
      MFMA_Q(0, 0);
      BAR();
      // -- g6: (mh0,nh1); stage A0(k2)h1
      READ_B(1, 1);
      if (more) STAGE_A(0, Ax, 1, k2);
      BAR(); WAIT_LGKM();
      MFMA_Q(0, 1);
      BAR();
      // -- g7: (mh1,nh0); stage B1(k3)h0
      READ_A(1, 1);
      if (more) STAGE_B(1, Bx, 0, k3);
      BAR(); WAIT_LGKM();
      MFMA_Q(1, 0);
      BAR();
      // -- g8: (mh1,nh1); stage B1(k3)h1; counted vmcnt
      if (more) STAGE_B(1, Bx, 1, k3);
      BAR();
      MFMA_Q(1, 1);
      if (more) {
        asm volatile("s_waitcnt vmcnt(4)" ::: "memory");
        __builtin_amdgcn_sched_barrier(0);
      }
      BAR();
    }

    // ---- epilogue for tile (bxxC,byyC,zC). No LDS, no barriers; stores
    // overlap next tile's early phases. D col=lane&15, row=quad*4+reg.
    u16* Cb = C + zC * sC +
              (size_t)(byyC * 256 + wm * 128) * ldc +
              (size_t)bxxC * 256 + wn * 64;
    if (MODE == 0) {
#pragma unroll
      for (int i = 0; i < 8; i++)
#pragma unroll
        for (int j = 0; j < 4; j++)
#pragma unroll
          for (int r = 0; r < 4; r++) {
            int row = i * 16 + quad * 4 + r;
            int col = j * 16 + lrow;
            Cb[(size_t)row * ldc + col] = f2bf(acc[i][j][r] * cscale);
          }
    } else {
      float* Lb = Lrow + zC * NN + (size_t)byyC * 256 + wm * 128;
#pragma unroll
      for (int i = 0; i < 8; i++)
#pragma unroll
        for (int r = 0; r < 4; r++) {
          int row = i * 16 + quad * 4 + r;
          float rs = 0.f;
#pragma unroll
          for (int j = 0; j < 4; j++) {
            int col = j * 16 + lrow;
            float e = __expf(fminf(acc[i][j][r] * cscale, 10.f));
            Cb[(size_t)row * ldc + col] = f2h(e);
            rs += e;
          }
          rs += __shfl_xor(rs, 1); rs += __shfl_xor(rs, 2);
          rs += __shfl_xor(rs, 4); rs += __shfl_xor(rs, 8);
          if (lrow == 0) atomicAdd(&Lb[row], rs);
        }
    }

    if (!lastTile) {
#pragma unroll
      for (int i = 0; i < 8; i++)
#pragma unroll
        for (int j = 0; j < 4; j++) acc[i][j] = (f32x4){0.f, 0.f, 0.f, 0.f};
    }
    bxxC = bxxN; byyC = byyN; zC = zN; AbC = AbN; BbC = BbN;
  }
}

// ---------------------------------------------------------------------------
// fp32 -> bf16 cast for BOTH x (blocks [0,8192)) and Wq (blocks [8192,8320)).
// ---------------------------------------------------------------------------
__global__ void cast_two(const float* __restrict__ x, u16* __restrict__ xb,
                         const float* __restrict__ w, u16* __restrict__ wb) {
  int bid = blockIdx.x;
  const float* src;
  u16* dst;
  size_t i;
  if (bid < 8192) {
    src = x;  dst = xb; i = ((size_t)bid * 256 + threadIdx.x) * 8;
  } else {
    src = w;  dst = wb; i = ((size_t)(bid - 8192) * 256 + threadIdx.x) * 8;
  }
  float4 f0 = *(const float4*)(src + i);
  float4 f1 = *(const float4*)(src + i + 4);
  u16x8 r;
  r[0] = f2bf(f0.x); r[1] = f2bf(f0.y); r[2] = f2bf(f0.z); r[3] = f2bf(f0.w);
  r[4] = f2bf(f1.x); r[5] = f2bf(f1.y); r[6] = f2bf(f1.z); r[7] = f2bf(f1.w);
  *(u16x8*)(dst + i) = r;
}

// ---------------------------------------------------------------------------
// c[z*NN+m] += sum_n E[z][n0+n][m] / L[z*NN+n0+n]     (E already exp'ed)
// grid (n-chunks of 128, z), 256 thr, 8 cols/thread (16B/lane loads, G13).
// ---------------------------------------------------------------------------
__global__ void col_sum(const __half* __restrict__ E, const float* __restrict__ L,
                        float* __restrict__ c) {
  int m8 = threadIdx.x * 8;              // 256 thr x 8 = 2048 cols
  int n0 = blockIdx.x * 128;
  int z  = blockIdx.y;
  const u16* Ep = (const u16*)E + ((size_t)z * NN + n0) * NN + m8;
  const float* lp = L + (size_t)z * NN + n0;
  float a[8] = {0.f, 0.f, 0.f, 0.f, 0.f, 0.f, 0.f, 0.f};
#pragma unroll 2
  for (int n = 0; n < 128; n++) {
    u16x8 h = *(const u16x8*)&Ep[(size_t)n * NN];
    float il = 1.0f / lp[n];
#pragma unroll
    for (int j = 0; j < 8; j++) a[j] += h2f(h[j]) * il;
  }
  float* cb = c + (size_t)z * NN + m8;
#pragma unroll
  for (int j = 0; j < 8; j++) atomicAdd(&cb[j], a[j]);
}

// ---------------------------------------------------------------------------
// t[b][d] += sum_m c[b][m] * xb[b][m][d]
// grid (B, 16 m-chunks of 128), 256 thr = 64 d-groups x 4 m-groups;
// u16x8 loads (16B/lane), LDS partial-reduce, 512 atomics/block.
// ---------------------------------------------------------------------------
__global__ void tx_accum(const u16* __restrict__ xb, const float* __restrict__ c,
                         float* __restrict__ t) {
  int b = blockIdx.x, mc = blockIdx.y;
  int dgrp = threadIdx.x & 63;           // 64 x 8 = 512 d
  int mgrp = threadIdx.x >> 6;           // 4 x 32 = 128 m
  int d8 = dgrp * 8;
  const u16* vp = xb + ((size_t)b * NN + mc * 128 + mgrp * 32) * ND;
  const float* cp = c + b * NN + mc * 128 + mgrp * 32;
  float a[8] = {0.f, 0.f, 0.f, 0.f, 0.f, 0.f, 0.f, 0.f};
#pragma unroll 2
  for (int m = 0; m < 32; m++) {
    float cm = cp[m];
    u16x8 v = *(const u16x8*)&vp[(size_t)m * ND + d8];
#pragma unroll
    for (int j = 0; j < 8; j++) a[j] += cm * bf2f(v[j]);
  }
  __shared__ float smr[4][512];
#pragma unroll
  for (int j = 0; j < 8; j++) smr[mgrp][d8 + j] = a[j];
  __syncthreads();
  if (mgrp == 0) {
    float* tb = t + b * ND + d8;
#pragma unroll
    for (int j = 0; j < 8; j++)
      atomicAdd(&tb[j], a[j] + smr[1][d8 + j] + smr[2][d8 + j] + smr[3][d8 + j]);
  }
}

// ---------------------------------------------------------------------------
// out[b][d] = (1/NN) * sum_l t[b][l] * Wv[l][d]   (Wv fp32, full precision)
// grid (B, 8 d-chunks of 64), 256 thr = 64 d x 4 l-groups, LDS reduce.
// ---------------------------------------------------------------------------
__global__ void final_wv(const float* __restrict__ t, const float* __restrict__ Wv,
                         float* __restrict__ out) {
  int b = blockIdx.x;
  int d = blockIdx.y * 64 + (threadIdx.x & 63);
  int lgrp = threadIdx.x >> 6;           // 4 x 128 = 512 l
  const float* tb = t + b * ND + lgrp * 128;
  const float* wp = Wv + (size_t)lgrp * 128 * ND + d;
  float a = 0.f;
#pragma unroll 4
  for (int l = 0; l < 128; l++) a += tb[l] * wp[(size_t)l * ND];
  __shared__ float smr[4][64];
  smr[lgrp][threadIdx.x & 63] = a;
  __syncthreads();
  if (lgrp == 0)
    out[b * ND + d] = (a + smr[1][threadIdx.x & 63] + smr[2][threadIdx.x & 63] +
                       smr[3][threadIdx.x & 63]) * (1.f / (float)NN);
}

// ---------------------------------------------------------------------------
extern "C" void kernel_launch(void* const* d_in, const int* in_sizes, int n_in,
                              void* d_out, int out_size, void* d_ws, size_t ws_size,
                              hipStream_t stream) {
  const float* x  = (const float*)d_in[0];  // [16,2048,512] fp32
  const float* Wk = (const float*)d_in[1];  // [512,512]     fp32
  const float* Wq = (const float*)d_in[2];  // [512,512]     fp32
  const float* Wv = (const float*)d_in[3];  // [512,512]     fp32
  float* out = (float*)d_out;               // [16,512]      fp32

  // --- small fixed region (~1.3 MB). L,c,t contiguous (one memset). ---
  char* ws = (char*)d_ws;
  size_t off = 0;
  float* L   = (float*)(ws + off); off += (size_t)NB * NN * 4;     // 128 KB
  float* c   = (float*)(ws + off); off += (size_t)NB * NN * 4;     // 128 KB
  float* t   = (float*)(ws + off); off += (size_t)NB * ND * 4;     // 32 KB
  u16* Wqb   = (u16*)(ws + off);   off += (size_t)ND * ND * 2;     // 512 KB
  u16* Mt    = (u16*)(ws + off);   off += (size_t)ND * ND * 2;     // 512 KB
  const size_t small_total = off;

  // --- big region: xb (33.6) + y (33.6) + E chunk (adaptive) ---
  const size_t XBSZ = (size_t)NB * NN * ND * 2;   // 33.55 MB
  const size_t SB1  = (size_t)NN * NN * 2;        // 8.39 MB / batch of E
  u16* xb   = (u16*)(ws + small_total);
  u16* y    = (u16*)(ws + small_total + XBSZ);
  __half* E = (__half*)(ws + small_total + 2 * XBSZ);
  size_t srem = ws_size > small_total + 2 * XBSZ
              ? ws_size - small_total - 2 * XBSZ : 0;
  int chb = 0, sr = 128;
  if      (srem >= 16 * SB1) chb = 16;
  else if (srem >=  8 * SB1) chb = 8;
  else if (srem >=  4 * SB1) chb = 4;
  else if (srem >=  2 * SB1) chb = 2;
  else if (srem >=  1 * SB1) chb = 1;
  else {
    if      (srem >= (size_t)1024 * NN * 2) sr = 1024;
    else if (srem >= (size_t)512  * NN * 2) sr = 512;
    else if (srem >= (size_t)256  * NN * 2) sr = 256;
  }

  hipMemsetAsync(L, 0, (size_t)(2 * NB * NN + NB * ND) * sizeof(float), stream);

  // xb = bf16(x) and Wqb = bf16(Wq) in one launch
  cast_two<<<8320, 256, 0, stream>>>(x, xb, Wq, Wqb);

  // Mt[n][k] = SSCALE * sum_l Wk[n][l]*Wq[k][l]  (tiny — 128² kernel)
  gemm_bt<0, true><<<dim3(4, 4, 1), 256, 0, stream>>>(
      Wk, Wqb, Mt, nullptr, ND, ND, ND, ND, 0, 0, 0, SSCALE);

  // y = x * M  (256 tiles: tgxs=1, tgys=7; tpb=1 — identical to r10 path)
  gemm256<0><<<dim3(256, 1, 1), 512, 0, stream>>>(
      xb, Mt, y, nullptr, ND, ND, ND, 1, 256, 1, 7, 0, 0, 0, 1.0f);

  const long long sR = (long long)NN * ND;   // per-batch row stride (y, xb)
  const long long sS = (long long)NN * NN;

  if (chb >= 1) {
    for (int cc = 0; cc < NB / chb; ++cc) {
      size_t o = (size_t)cc * chb * NN;
      // E = exp(y_b * xb_b^T), row sums into L. tiles = 64*chb (tgxs=3,
      // tgys=3, z fastest-last); STRIDE-persistent: tile = bid + stride*ti.
      int tiles  = 64 * chb;
      int tpb    = tiles >= 1024 ? 4 : (tiles >= 512 ? 2 : 1);
      int stride = tiles / tpb;
      gemm256<1><<<dim3(stride, 1, 1), 512, 0, stream>>>(
          y + o * ND, xb + o * ND, (u16*)E, L + o, ND, ND, NN,
          tpb, stride, 3, 3, sR, sR, sS, 1.0f);
      col_sum<<<dim3(16, chb), 256, 0, stream>>>(E, L + o, c + o);
    }
  } else if (sr >= 256) {  // sub-batch chunks of sr rows (tpb=1)
    for (int b = 0; b < NB; ++b) {
      for (int ch = 0; ch < NN / sr; ++ch) {
        size_t o = (size_t)b * NN + (size_t)ch * sr;
        int tgys = (sr == 1024) ? 2 : (sr == 512) ? 1 : 0;
        int tiles = 8 << tgys;
        gemm256<1><<<dim3(tiles, 1, 1), 512, 0, stream>>>(
            y + o * ND, xb + (size_t)b * NN * ND, (u16*)E, L + o,
            ND, ND, NN, 1, tiles, 3, tgys, 0, 0, 0, 1.0f);
        col_sum<<<dim3(sr / 128, 1), 256, 0, stream>>>(E, L + o, c + b * NN);
      }
    }
  } else {  // tiny workspace fallback: old 128² kernel
    for (int b = 0; b < NB; ++b) {
      for (int ch = 0; ch < NN / sr; ++ch) {
        size_t o = (size_t)b * NN + (size_t)ch * sr;
        gemm_bt<1, false><<<dim3(16, sr / 128, 1), 256, 0, stream>>>(
            y + o * ND, xb + (size_t)b * NN * ND, (u16*)E, L + o,
            ND, ND, NN, ND, 0, 0, 0, 1.0f);
        col_sum<<<dim3(sr / 128, 1), 256, 0, stream>>>(E, L + o, c + b * NN);
      }
    }
  }

  // t[b] = c_b^T x_b ;  out = (t * Wv) / NN
  tx_accum<<<dim3(NB, 16), 256, 0, stream>>>(xb, c, t);
  final_wv<<<dim3(NB, 8), 256, 0, stream>>>(t, Wv, out);
  (void)in_sizes; (void)n_in; (void)out_size;
}

// Round 12
// 326.502 us; speedup vs baseline: 1.2243x; 1.2243x over previous
//
#include <hip/hip_runtime.h>
#include <hip/hip_bf16.h>
#include <hip/hip_fp16.h>
#include <stdint.h>

// B=16, N=2048, D=512. Inputs/outputs FLOAT32; internal bf16/fp16.
// Algebra: S = x(WqWk^T)x^T ; out*N = (c^T x)Wv  -> q,k,v never materialized.
// Ladder: r2=348.8 | r4 LDS-epi REF | r5 T1 REF | r6 recompute REF | r7 NT
// REF | r8=313.8 | r9 persistent REF | r10=312.5 | r11 stride-persistent REF
// (WRITE +60MB both persistent variants: overlapped-epilogue partial-line
// eviction; FETCH +105MB: generation drift). This round: r10 minus two
// dispatches (memset folded into cast; Mt-GEMM converts both operands).
#define NB 16
#define NN 2048
#define ND 512
#define SSCALE 0.044194173824159216f        // 1/sqrt(512)

typedef unsigned short u16;
typedef unsigned int u32;
typedef float f32x4 __attribute__((ext_vector_type(4)));
typedef __bf16 bf16x8 __attribute__((ext_vector_type(8)));
typedef unsigned short u16x8 __attribute__((ext_vector_type(8)));

__device__ __forceinline__ float bf2f(u16 h) {
  union { u32 u; float f; } v; v.u = ((u32)h) << 16; return v.f;
}
__device__ __forceinline__ u16 f2bf(float f) {
  union { float f; u32 u; } v; v.f = f;
  u32 r = v.u + 0x7fffu + ((v.u >> 16) & 1u);   // RNE
  return (u16)(r >> 16);
}
__device__ __forceinline__ u16 f2h(float f) {
  __half h = __float2half(f);
  union { __half h; u16 u; } v; v.h = h; return v.u;
}
__device__ __forceinline__ float h2f(u16 u) {
  union { u16 u; __half h; } v; v.u = u; return __half2float(v.h);
}

// async global->LDS, 16B/lane (wave-uniform base + lane*16 contract).
__device__ __forceinline__ void async16(const void* g, void* l) {
  __builtin_amdgcn_global_load_lds(
      (const __attribute__((address_space(1))) u32*)g,
      (__attribute__((address_space(3))) u32*)l,
      16, 0, 0);
}

// ===========================================================================
// OLD 128x128 kernel (m97 structure) — kept for the tiny Mt GEMM (ABF32:
// BOTH operands fp32, converted in-register while staging) and the
// small-workspace fallback (ABF32=false: bf16 A,B via async16).
// ===========================================================================
template <int MODE, bool ABF32>
__global__ __launch_bounds__(256, 2) void gemm_bt(
    const void* __restrict__ Av, const void* __restrict__ Bv, u16* __restrict__ C,
    float* __restrict__ Lrow, int lda, int ldb, int ldc, int K,
    long long sA, long long sB, long long sC, float cscale) {
  const int tid  = threadIdx.x;
  const int w    = tid >> 6;
  const int lane = tid & 63;
  const int wm   = w >> 1, wn = w & 1;
  const int lrow = lane & 15, quad = lane >> 4;
  const long long z = blockIdx.z;

  const float* Abf = (const float*)Av + z * sA + (size_t)blockIdx.y * 128 * lda;
  const u16*   Abh = (const u16*)Av   + z * sA + (size_t)blockIdx.y * 128 * lda;
  const float* Bbf = (const float*)Bv + z * sB + (size_t)blockIdx.x * 128 * ldb;
  const u16*   Bbh = (const u16*)Bv   + z * sB + (size_t)blockIdx.x * 128 * ldb;

  __shared__ __align__(16) u16 lds_a[128 * 32];
  __shared__ __align__(16) u16 lds_b[128 * 32];

  f32x4 acc[4][4];
#pragma unroll
  for (int i = 0; i < 4; i++)
#pragma unroll
    for (int j = 0; j < 4; j++) acc[i][j] = (f32x4){0.f, 0.f, 0.f, 0.f};

  for (int k0 = 0; k0 < K; k0 += 32) {
    if (k0) __syncthreads();
    if (ABF32) {
      u16x8 va[2], vb[2];
#pragma unroll
      for (int t = 0; t < 2; t++) {
        int ch  = t * 256 + tid;
        int row = ch >> 2;
        int cc  = (ch & 3) * 8;
        const float4* pa = (const float4*)(Abf + (size_t)row * lda + k0 + cc);
        float4 a0 = pa[0], a1 = pa[1];
        const float4* pb = (const float4*)(Bbf + (size_t)row * ldb + k0 + cc);
        float4 b0 = pb[0], b1 = pb[1];
        u16x8 ra, rb;
        ra[0] = f2bf(a0.x); ra[1] = f2bf(a0.y); ra[2] = f2bf(a0.z); ra[3] = f2bf(a0.w);
        ra[4] = f2bf(a1.x); ra[5] = f2bf(a1.y); ra[6] = f2bf(a1.z); ra[7] = f2bf(a1.w);
        rb[0] = f2bf(b0.x); rb[1] = f2bf(b0.y); rb[2] = f2bf(b0.z); rb[3] = f2bf(b0.w);
        rb[4] = f2bf(b1.x); rb[5] = f2bf(b1.y); rb[6] = f2bf(b1.z); rb[7] = f2bf(b1.w);
        va[t] = ra; vb[t] = rb;
      }
#pragma unroll
      for (int t = 0; t < 2; t++) {
        *(u16x8*)&lds_a[(t * 256 + tid) * 8] = va[t];
        *(u16x8*)&lds_b[(t * 256 + tid) * 8] = vb[t];
      }
    } else {
#pragma unroll
      for (int t = 0; t < 2; t++) {
        int ch  = t * 256 + tid;
        int row = ch >> 2;
        int cc  = (ch & 3) * 8;
        async16(Abh + (size_t)row * lda + k0 + cc, &lds_a[ch * 8]);
        async16(Bbh + (size_t)row * ldb + k0 + cc, &lds_b[ch * 8]);
      }
    }
    __syncthreads();

    bf16x8 af[4], bfr[4];
#pragma unroll
    for (int i = 0; i < 4; i++) {
      af[i]  = *(const bf16x8*)&lds_a[(wm * 64 + i * 16 + lrow) * 32 + quad * 8];
      bfr[i] = *(const bf16x8*)&lds_b[(wn * 64 + i * 16 + lrow) * 32 + quad * 8];
    }
#pragma unroll
    for (int i = 0; i < 4; i++)
#pragma unroll
      for (int j = 0; j < 4; j++)
        acc[i][j] =
            __builtin_amdgcn_mfma_f32_16x16x32_bf16(af[i], bfr[j], acc[i][j], 0, 0, 0);
  }

  u16* Cb = C + z * sC + (size_t)blockIdx.y * 128 * ldc + (size_t)blockIdx.x * 128;
  if (MODE == 0) {
#pragma unroll
    for (int i = 0; i < 4; i++)
#pragma unroll
      for (int j = 0; j < 4; j++)
#pragma unroll
        for (int r = 0; r < 4; r++) {
          int row = wm * 64 + i * 16 + quad * 4 + r;
          int col = wn * 64 + j * 16 + lrow;
          Cb[(size_t)row * ldc + col] = f2bf(acc[i][j][r] * cscale);
        }
  } else {
    float* Lb = Lrow + z * NN + (size_t)blockIdx.y * 128;
#pragma unroll
    for (int i = 0; i < 4; i++)
#pragma unroll
      for (int r = 0; r < 4; r++) {
        int row = wm * 64 + i * 16 + quad * 4 + r;
        float rs = 0.f;
#pragma unroll
        for (int j = 0; j < 4; j++) {
          int col = wn * 64 + j * 16 + lrow;
          float e = __expf(fminf(acc[i][j][r] * cscale, 10.f));
          Cb[(size_t)row * ldc + col] = f2h(e);
          rs += e;
        }
        rs += __shfl_xor(rs, 1); rs += __shfl_xor(rs, 2);
        rs += __shfl_xor(rs, 4); rs += __shfl_xor(rs, 8);
        if (lrow == 0) atomicAdd(&Lb[row], rs);
      }
  }
}

// ===========================================================================
// 256x256 8-phase GEMM (T2 swizzle + T3/T4 counted vmcnt + T5 setprio).
// NON-persistent (r9/r11 refuted), no T1 (r5), plain cached direct stores
// (r4/r7). Grid (8,8,z): dispatcher generations = 4-batch/16MB L2-resident
// cohorts. MODE 0: store bf16(C*cscale). MODE 1: store fp16(exp(min(C,10)))
// + row expsum atomicAdd into Lrow.
// ===========================================================================
__device__ __forceinline__ void stage_half(const u16* __restrict__ g, int ld,
                                           int row0, int k0,
                                           u16* __restrict__ l, int tid) {
  int r  = tid >> 3;                    // 0..63
  int Lc = (tid & 7) ^ (r & 7);         // inverse-swizzled source chunk
  async16(g + (size_t)(row0 + r) * ld + k0 + Lc * 8, l + tid * 8);
  async16(g + (size_t)(row0 + 64 + r) * ld + k0 + Lc * 8, l + 4096 + tid * 8);
}

__device__ __forceinline__ bf16x8 ldf(const u16* __restrict__ h, int rbase,
                                      int lrow, int quad, int ks) {
  int rr = rbase + lrow;
  int pc = (ks * 4 + quad) ^ (lrow & 7);  // swizzled read chunk
  return *(const bf16x8*)&h[rr * 64 + pc * 8];
}

#define BAR() __builtin_amdgcn_s_barrier()
#define WAIT_LGKM()                                          \
  do {                                                       \
    asm volatile("s_waitcnt lgkmcnt(0)" ::: "memory");       \
    __builtin_amdgcn_sched_barrier(0);                       \
  } while (0)

#define READ_A(p, mh)                                                        \
  _Pragma("unroll") for (int i2 = 0; i2 < 4; ++i2)                           \
  _Pragma("unroll") for (int ks = 0; ks < 2; ++ks)                           \
      af[i2][ks] = ldf(sm + (p) * 32768 + wm * 8192, ((mh)*4 + i2) * 16,     \
                       lrow, quad, ks);

#define READ_B(p, nh)                                                        \
  _Pragma("unroll") for (int j2 = 0; j2 < 2; ++j2)                           \
  _Pragma("unroll") for (int ks = 0; ks < 2; ++ks)                           \
      bq[(nh)*2 + j2][ks] =                                                  \
          ldf(sm + (p) * 32768 + 16384 + (wn >> 1) * 8192,                   \
              (wn & 1) * 64 + ((nh)*2 + j2) * 16, lrow, quad, ks);

#define MFMA_Q(mh, nh)                                                       \
  __builtin_amdgcn_s_setprio(1);                                             \
  _Pragma("unroll") for (int i2 = 0; i2 < 4; ++i2)                           \
  _Pragma("unroll") for (int j2 = 0; j2 < 2; ++j2)                           \
  _Pragma("unroll") for (int ks = 0; ks < 2; ++ks)                           \
      acc[(mh)*4 + i2][(nh)*2 + j2] = __builtin_amdgcn_mfma_f32_16x16x32_bf16( \
          af[i2][ks], bq[(nh)*2 + j2][ks], acc[(mh)*4 + i2][(nh)*2 + j2],    \
          0, 0, 0);                                                          \
  __builtin_amdgcn_s_setprio(0);

#define STAGE_A(p, h, kt) \
  stage_half(Ab, lda, (h)*128, (kt)*64, sm + (p)*32768 + (h)*8192, tid)
#define STAGE_B(p, h, kt) \
  stage_half(Bb, ldb, (h)*128, (kt)*64, sm + (p)*32768 + 16384 + (h)*8192, tid)

template <int MODE>
__global__ __launch_bounds__(512, 2) void gemm256(
    const u16* __restrict__ A, const u16* __restrict__ B, u16* __restrict__ C,
    float* __restrict__ Lrow, int lda, int ldb, int ldc, int K,
    long long sA, long long sB, long long sC, float cscale) {
  const int tid  = threadIdx.x;
  const int wid  = tid >> 6, lane = tid & 63;
  const int wm   = wid >> 2, wn = wid & 3;   // 2 M-waves x 4 N-waves
  const int lrow = lane & 15, quad = lane >> 4;

  const int bxx = blockIdx.x;
  const int byy = blockIdx.y;
  const long long z = blockIdx.z;

  const u16* Ab = A + z * sA + (size_t)byy * 256 * lda;
  const u16* Bb = B + z * sB + (size_t)bxx * 256 * ldb;

  __shared__ __align__(16) u16 sm[65536];   // 128 KiB

  f32x4 acc[8][4];
#pragma unroll
  for (int i = 0; i < 8; i++)
#pragma unroll
    for (int j = 0; j < 4; j++) acc[i][j] = (f32x4){0.f, 0.f, 0.f, 0.f};

  bf16x8 af[4][2];   // current A m-half frags (4 mfrags x 2 ksteps)
  bf16x8 bq[4][2];   // current B tile frags  (4 nfrags x 2 ksteps)

  const int NITER = K >> 7;   // K/128 tile-pairs (K=512 -> 4)

  // ---- prologue: A0(0), B0(0), B1(1); allow B1(1) in flight
  STAGE_A(0, 0, 0); STAGE_A(0, 1, 0);
  STAGE_B(0, 0, 0); STAGE_B(0, 1, 0);
  STAGE_B(1, 0, 1); STAGE_B(1, 1, 1);
  asm volatile("s_waitcnt vmcnt(4)" ::: "memory");
  __builtin_amdgcn_sched_barrier(0);
  BAR();

  for (int it = 0; it < NITER; ++it) {
    const int t = 2 * it;
    const bool more = (it + 1 < NITER);

    // -- g1: tile t (p0), quadrant (mh0,nh0); stage A1h0(t+1)
    READ_A(0, 0); READ_B(0, 0);
    STAGE_A(1, 0, t + 1);
    BAR(); WAIT_LGKM();
    MFMA_Q(0, 0);
    BAR();
    // -- g2: (mh0,nh1); stage A1h1(t+1)
    READ_B(0, 1);
    STAGE_A(1, 1, t + 1);
    BAR(); WAIT_LGKM();
    MFMA_Q(0, 1);
    BAR();
    // -- g3: (mh1,nh0); stage B0h0(t+2)
    READ_A(0, 1);
    if (more) STAGE_B(0, 0, t + 2);
    BAR(); WAIT_LGKM();
    MFMA_Q(1, 0);
    BAR();
    // -- g4: (mh1,nh1); stage B0h1(t+2); counted vmcnt
    if (more) STAGE_B(0, 1, t + 2);
    BAR();
    MFMA_Q(1, 1);
    if (more) { asm volatile("s_waitcnt vmcnt(4)" ::: "memory"); }
    else      { asm volatile("s_waitcnt vmcnt(0)" ::: "memory"); }
    __builtin_amdgcn_sched_barrier(0);
    BAR();
    // -- g5: tile t+1 (p1), (mh0,nh0); stage A0h0(t+2)
    READ_A(1, 0); READ_B(1, 0);
    if (more) STAGE_A(0, 0, t + 2);
    BAR(); WAIT_LGKM();
    MFMA_Q(0, 0);
    BAR();
    // -- g6: (mh0,nh1); stage A0h1(t+2)
    READ_B(1, 1);
    if (more) STAGE_A(0, 1, t + 2);
    BAR(); WAIT_LGKM();
    MFMA_Q(0, 1);
    BAR();
    // -- g7: (mh1,nh0); stage B1h0(t+3)
    READ_A(1, 1);
    if (more) STAGE_B(1, 0, t + 3);
    BAR(); WAIT_LGKM();
    MFMA_Q(1, 0);
    BAR();
    // -- g8: (mh1,nh1); stage B1h1(t+3); counted vmcnt
    if (more) STAGE_B(1, 1, t + 3);
    BAR();
    MFMA_Q(1, 1);
    if (more) {
      asm volatile("s_waitcnt vmcnt(4)" ::: "memory");
      __builtin_amdgcn_sched_barrier(0);
    }
    BAR();
  }

  // ---- epilogue (direct cached stores). D col=lane&15, row=quad*4+reg
  u16* Cb = C + z * sC +
            (size_t)(byy * 256 + wm * 128) * ldc +
            (size_t)bxx * 256 + wn * 64;
  if (MODE == 0) {
#pragma unroll
    for (int i = 0; i < 8; i++)
#pragma unroll
      for (int j = 0; j < 4; j++)
#pragma unroll
        for (int r = 0; r < 4; r++) {
          int row = i * 16 + quad * 4 + r;
          int col = j * 16 + lrow;
          Cb[(size_t)row * ldc + col] = f2bf(acc[i][j][r] * cscale);
        }
  } else {
    float* Lb = Lrow + z * NN + (size_t)byy * 256 + wm * 128;
#pragma unroll
    for (int i = 0; i < 8; i++)
#pragma unroll
      for (int r = 0; r < 4; r++) {
        int row = i * 16 + quad * 4 + r;
        float rs = 0.f;
#pragma unroll
        for (int j = 0; j < 4; j++) {
          int col = j * 16 + lrow;
          float e = __expf(fminf(acc[i][j][r] * cscale, 10.f));
          Cb[(size_t)row * ldc + col] = f2h(e);
          rs += e;
        }
        rs += __shfl_xor(rs, 1); rs += __shfl_xor(rs, 2);
        rs += __shfl_xor(rs, 4); rs += __shfl_xor(rs, 8);
        if (lrow == 0) atomicAdd(&Lb[row], rs);
      }
  }
}

// ---------------------------------------------------------------------------
// fp32 -> bf16 cast for x (blocks [0,8192)) + zero of L/c/t (blocks
// [8192,8264): 72 blocks x 1024 floats = 294912 B). Replaces the memset
// dispatch; runs first in-stream so all atomic targets are zeroed.
// ---------------------------------------------------------------------------
__global__ void cast_zero(const float* __restrict__ x, u16* __restrict__ xb,
                          float* __restrict__ zbase) {
  int bid = blockIdx.x;
  if (bid < 8192) {
    size_t i = ((size_t)bid * 256 + threadIdx.x) * 8;
    float4 f0 = *(const float4*)(x + i);
    float4 f1 = *(const float4*)(x + i + 4);
    u16x8 r;
    r[0] = f2bf(f0.x); r[1] = f2bf(f0.y); r[2] = f2bf(f0.z); r[3] = f2bf(f0.w);
    r[4] = f2bf(f1.x); r[5] = f2bf(f1.y); r[6] = f2bf(f1.z); r[7] = f2bf(f1.w);
    *(u16x8*)(xb + i) = r;
  } else {
    size_t i = ((size_t)(bid - 8192) * 256 + threadIdx.x) * 4;
    *(f32x4*)(zbase + i) = (f32x4){0.f, 0.f, 0.f, 0.f};
  }
}

// ---------------------------------------------------------------------------
// c[z*NN+m] += sum_n E[z][n0+n][m] / L[z*NN+n0+n]     (E already exp'ed)
// grid (n-chunks of 128, z), 256 thr, 8 cols/thread (16B/lane loads, G13).
// ---------------------------------------------------------------------------
__global__ void col_sum(const __half* __restrict__ E, const float* __restrict__ L,
                        float* __restrict__ c) {
  int m8 = threadIdx.x * 8;              // 256 thr x 8 = 2048 cols
  int n0 = blockIdx.x * 128;
  int z  = blockIdx.y;
  const u16* Ep = (const u16*)E + ((size_t)z * NN + n0) * NN + m8;
  const float* lp = L + (size_t)z * NN + n0;
  float a[8] = {0.f, 0.f, 0.f, 0.f, 0.f, 0.f, 0.f, 0.f};
#pragma unroll 2
  for (int n = 0; n < 128; n++) {
    u16x8 h = *(const u16x8*)&Ep[(size_t)n * NN];
    float il = 1.0f / lp[n];
#pragma unroll
    for (int j = 0; j < 8; j++) a[j] += h2f(h[j]) * il;
  }
  float* cb = c + (size_t)z * NN + m8;
#pragma unroll
  for (int j = 0; j < 8; j++) atomicAdd(&cb[j], a[j]);
}

// ---------------------------------------------------------------------------
// t[b][d] += sum_m c[b][m] * xb[b][m][d]
// grid (B, 16 m-chunks of 128), 256 thr = 64 d-groups x 4 m-groups;
// u16x8 loads (16B/lane), LDS partial-reduce, 512 atomics/block.
// ---------------------------------------------------------------------------
__global__ void tx_accum(const u16* __restrict__ xb, const float* __restrict__ c,
                         float* __restrict__ t) {
  int b = blockIdx.x, mc = blockIdx.y;
  int dgrp = threadIdx.x & 63;           // 64 x 8 = 512 d
  int mgrp = threadIdx.x >> 6;           // 4 x 32 = 128 m
  int d8 = dgrp * 8;
  const u16* vp = xb + ((size_t)b * NN + mc * 128 + mgrp * 32) * ND;
  const float* cp = c + b * NN + mc * 128 + mgrp * 32;
  float a[8] = {0.f, 0.f, 0.f, 0.f, 0.f, 0.f, 0.f, 0.f};
#pragma unroll 2
  for (int m = 0; m < 32; m++) {
    float cm = cp[m];
    u16x8 v = *(const u16x8*)&vp[(size_t)m * ND + d8];
#pragma unroll
    for (int j = 0; j < 8; j++) a[j] += cm * bf2f(v[j]);
  }
  __shared__ float smr[4][512];
#pragma unroll
  for (int j = 0; j < 8; j++) smr[mgrp][d8 + j] = a[j];
  __syncthreads();
  if (mgrp == 0) {
    float* tb = t + b * ND + d8;
#pragma unroll
    for (int j = 0; j < 8; j++)
      atomicAdd(&tb[j], a[j] + smr[1][d8 + j] + smr[2][d8 + j] + smr[3][d8 + j]);
  }
}

// ---------------------------------------------------------------------------
// out[b][d] = (1/NN) * sum_l t[b][l] * Wv[l][d]   (Wv fp32, full precision)
// grid (B, 8 d-chunks of 64), 256 thr = 64 d x 4 l-groups, LDS reduce.
// ---------------------------------------------------------------------------
__global__ void final_wv(const float* __restrict__ t, const float* __restrict__ Wv,
                         float* __restrict__ out) {
  int b = blockIdx.x;
  int d = blockIdx.y * 64 + (threadIdx.x & 63);
  int lgrp = threadIdx.x >> 6;           // 4 x 128 = 512 l
  const float* tb = t + b * ND + lgrp * 128;
  const float* wp = Wv + (size_t)lgrp * 128 * ND + d;
  float a = 0.f;
#pragma unroll 4
  for (int l = 0; l < 128; l++) a += tb[l] * wp[(size_t)l * ND];
  __shared__ float smr[4][64];
  smr[lgrp][threadIdx.x & 63] = a;
  __syncthreads();
  if (lgrp == 0)
    out[b * ND + d] = (a + smr[1][threadIdx.x & 63] + smr[2][threadIdx.x & 63] +
                       smr[3][threadIdx.x & 63]) * (1.f / (float)NN);
}

// ---------------------------------------------------------------------------
extern "C" void kernel_launch(void* const* d_in, const int* in_sizes, int n_in,
                              void* d_out, int out_size, void* d_ws, size_t ws_size,
                              hipStream_t stream) {
  const float* x  = (const float*)d_in[0];  // [16,2048,512] fp32
  const float* Wk = (const float*)d_in[1];  // [512,512]     fp32
  const float* Wq = (const float*)d_in[2];  // [512,512]     fp32
  const float* Wv = (const float*)d_in[3];  // [512,512]     fp32
  float* out = (float*)d_out;               // [16,512]      fp32

  // --- small fixed region. L,c,t contiguous (zeroed by cast_zero). ---
  char* ws = (char*)d_ws;
  size_t off = 0;
  float* L   = (float*)(ws + off); off += (size_t)NB * NN * 4;     // 128 KB
  float* c   = (float*)(ws + off); off += (size_t)NB * NN * 4;     // 128 KB
  float* t   = (float*)(ws + off); off += (size_t)NB * ND * 4;     // 32 KB
  u16* Mt    = (u16*)(ws + off);   off += (size_t)ND * ND * 2;     // 512 KB
  const size_t small_total = off;

  // --- big region: xb (33.6) + y (33.6) + E chunk (adaptive) ---
  const size_t XBSZ = (size_t)NB * NN * ND * 2;   // 33.55 MB
  const size_t SB1  = (size_t)NN * NN * 2;        // 8.39 MB / batch of E
  u16* xb   = (u16*)(ws + small_total);
  u16* y    = (u16*)(ws + small_total + XBSZ);
  __half* E = (__half*)(ws + small_total + 2 * XBSZ);
  size_t srem = ws_size > small_total + 2 * XBSZ
              ? ws_size - small_total - 2 * XBSZ : 0;
  int chb = 0, sr = 128;
  if      (srem >= 16 * SB1) chb = 16;
  else if (srem >=  8 * SB1) chb = 8;
  else if (srem >=  4 * SB1) chb = 4;
  else if (srem >=  2 * SB1) chb = 2;
  else if (srem >=  1 * SB1) chb = 1;
  else {
    if      (srem >= (size_t)1024 * NN * 2) sr = 1024;
    else if (srem >= (size_t)512  * NN * 2) sr = 512;
    else if (srem >= (size_t)256  * NN * 2) sr = 256;
  }

  // xb = bf16(x) and zero L/c/t (2*16*2048 + 16*512 = 73728 floats = 72 blk)
  cast_zero<<<8264, 256, 0, stream>>>(x, xb, L);

  // Mt[n][k] = SSCALE * sum_l Wk[n][l]*Wq[k][l]  (both operands fp32)
  gemm_bt<0, true><<<dim3(4, 4, 1), 256, 0, stream>>>(
      Wk, Wq, Mt, nullptr, ND, ND, ND, ND, 0, 0, 0, SSCALE);

  // y = x * M   (M=32768, N=512, K=512) -> bf16, 256² 8-phase kernel
  gemm256<0><<<dim3(2, 128, 1), 512, 0, stream>>>(
      xb, Mt, y, nullptr, ND, ND, ND, ND, 0, 0, 0, 1.0f);

  const long long sR = (long long)NN * ND;   // per-batch row stride (y, xb)
  const long long sS = (long long)NN * NN;

  if (chb >= 1) {
    for (int cc = 0; cc < NB / chb; ++cc) {
      size_t o = (size_t)cc * chb * NN;
      // E = exp(y_b * xb_b^T), row sums into L
      gemm256<1><<<dim3(8, 8, chb), 512, 0, stream>>>(
          y + o * ND, xb + o * ND, (u16*)E, L + o, ND, ND, NN, ND,
          sR, sR, sS, 1.0f);
      col_sum<<<dim3(16, chb), 256, 0, stream>>>(E, L + o, c + o);
    }
  } else if (sr >= 256) {  // sub-batch chunks of sr rows, 256² kernel
    for (int b = 0; b < NB; ++b) {
      for (int ch = 0; ch < NN / sr; ++ch) {
        size_t o = (size_t)b * NN + (size_t)ch * sr;
        gemm256<1><<<dim3(8, sr / 256, 1), 512, 0, stream>>>(
            y + o * ND, xb + (size_t)b * NN * ND, (u16*)E, L + o,
            ND, ND, NN, ND, 0, 0, 0, 1.0f);
        col_sum<<<dim3(sr / 128, 1), 256, 0, stream>>>(E, L + o, c + b * NN);
      }
    }
  } else {  // tiny workspace fallback: old 128² kernel
    for (int b = 0; b < NB; ++b) {
      for (int ch = 0; ch < NN / sr; ++ch) {
        size_t o = (size_t)b * NN + (size_t)ch * sr;
        gemm_bt<1, false><<<dim3(16, sr / 128, 1), 256, 0, stream>>>(
            y + o * ND, xb + (size_t)b * NN * ND, (u16*)E, L + o,
            ND, ND, NN, ND, 0, 0, 0, 1.0f);
        col_sum<<<dim3(sr / 128, 1), 256, 0, stream>>>(E, L + o, c + b * NN);
      }
    }
  }

  // t[b] = c_b^T x_b ;  out = (t * Wv) / NN
  tx_accum<<<dim3(NB, 16), 256, 0, stream>>>(xb, c, t);
  final_wv<<<dim3(NB, 8), 256, 0, stream>>>(t, Wv, out);
  (void)in_sizes; (void)n_in; (void)out_size;
}

// Round 13
// 311.723 us; speedup vs baseline: 1.2824x; 1.0474x over previous
//
#include <hip/hip_runtime.h>
#include <hip/hip_bf16.h>
#include <hip/hip_fp16.h>
#include <stdint.h>

// B=16, N=2048, D=512. Inputs/outputs FLOAT32; internal bf16/fp16.
// Algebra: S = x(WqWk^T)x^T ; out*N = (c^T x)Wv  -> q,k,v never materialized.
// Ladder: r2=348.8 | r4 LDS-epi REF | r5 T1 REF | r6 recompute REF | r7 NT
// REF | r8=313.8 | r9 persistent REF | r10=312.5 BEST | r11 stride-persistent
// REF | r12 dispatch-merge REF (+14us: Mt ABF32 staging on serial chain).
// This round: exact r10 revert — bank the best state.
#define NB 16
#define NN 2048
#define ND 512
#define SSCALE 0.044194173824159216f        // 1/sqrt(512)

typedef unsigned short u16;
typedef unsigned int u32;
typedef float f32x4 __attribute__((ext_vector_type(4)));
typedef __bf16 bf16x8 __attribute__((ext_vector_type(8)));
typedef unsigned short u16x8 __attribute__((ext_vector_type(8)));

__device__ __forceinline__ float bf2f(u16 h) {
  union { u32 u; float f; } v; v.u = ((u32)h) << 16; return v.f;
}
__device__ __forceinline__ u16 f2bf(float f) {
  union { float f; u32 u; } v; v.f = f;
  u32 r = v.u + 0x7fffu + ((v.u >> 16) & 1u);   // RNE
  return (u16)(r >> 16);
}
__device__ __forceinline__ u16 f2h(float f) {
  __half h = __float2half(f);
  union { __half h; u16 u; } v; v.h = h; return v.u;
}
__device__ __forceinline__ float h2f(u16 u) {
  union { u16 u; __half h; } v; v.u = u; return __half2float(v.h);
}

// async global->LDS, 16B/lane (wave-uniform base + lane*16 contract).
__device__ __forceinline__ void async16(const void* g, void* l) {
  __builtin_amdgcn_global_load_lds(
      (const __attribute__((address_space(1))) u32*)g,
      (__attribute__((address_space(3))) u32*)l,
      16, 0, 0);
}

// ===========================================================================
// OLD 128x128 kernel (m97 structure) — kept for the tiny Mt GEMM (AF32 path)
// and the small-workspace fallback.
// ===========================================================================
template <int MODE, bool AF32>
__global__ __launch_bounds__(256, 2) void gemm_bt(
    const void* __restrict__ Av, const u16* __restrict__ B, u16* __restrict__ C,
    float* __restrict__ Lrow, int lda, int ldb, int ldc, int K,
    long long sA, long long sB, long long sC, float cscale) {
  const int tid  = threadIdx.x;
  const int w    = tid >> 6;
  const int lane = tid & 63;
  const int wm   = w >> 1, wn = w & 1;
  const int lrow = lane & 15, quad = lane >> 4;
  const long long z = blockIdx.z;

  const float* Abf = (const float*)Av + z * sA + (size_t)blockIdx.y * 128 * lda;
  const u16*   Abh = (const u16*)Av   + z * sA + (size_t)blockIdx.y * 128 * lda;
  const u16*   Bb  = B + z * sB + (size_t)blockIdx.x * 128 * ldb;

  __shared__ __align__(16) u16 lds_a[128 * 32];
  __shared__ __align__(16) u16 lds_b[128 * 32];

  f32x4 acc[4][4];
#pragma unroll
  for (int i = 0; i < 4; i++)
#pragma unroll
    for (int j = 0; j < 4; j++) acc[i][j] = (f32x4){0.f, 0.f, 0.f, 0.f};

  for (int k0 = 0; k0 < K; k0 += 32) {
    if (k0) __syncthreads();
    if (AF32) {
      u16x8 va[2];
#pragma unroll
      for (int t = 0; t < 2; t++) {
        int ch  = t * 256 + tid;
        int row = ch >> 2;
        int cc  = (ch & 3) * 8;
        const float4* p = (const float4*)(Abf + (size_t)row * lda + k0 + cc);
        float4 f0 = p[0], f1 = p[1];
        u16x8 r;
        r[0] = f2bf(f0.x); r[1] = f2bf(f0.y); r[2] = f2bf(f0.z); r[3] = f2bf(f0.w);
        r[4] = f2bf(f1.x); r[5] = f2bf(f1.y); r[6] = f2bf(f1.z); r[7] = f2bf(f1.w);
        va[t] = r;
        async16(Bb + (size_t)row * ldb + k0 + cc, &lds_b[ch * 8]);
      }
#pragma unroll
      for (int t = 0; t < 2; t++) *(u16x8*)&lds_a[(t * 256 + tid) * 8] = va[t];
    } else {
#pragma unroll
      for (int t = 0; t < 2; t++) {
        int ch  = t * 256 + tid;
        int row = ch >> 2;
        int cc  = (ch & 3) * 8;
        async16(Abh + (size_t)row * lda + k0 + cc, &lds_a[ch * 8]);
        async16(Bb  + (size_t)row * ldb + k0 + cc, &lds_b[ch * 8]);
      }
    }
    __syncthreads();

    bf16x8 af[4], bfr[4];
#pragma unroll
    for (int i = 0; i < 4; i++) {
      af[i]  = *(const bf16x8*)&lds_a[(wm * 64 + i * 16 + lrow) * 32 + quad * 8];
      bfr[i] = *(const bf16x8*)&lds_b[(wn * 64 + i * 16 + lrow) * 32 + quad * 8];
    }
#pragma unroll
    for (int i = 0; i < 4; i++)
#pragma unroll
      for (int j = 0; j < 4; j++)
        acc[i][j] =
            __builtin_amdgcn_mfma_f32_16x16x32_bf16(af[i], bfr[j], acc[i][j], 0, 0, 0);
  }

  u16* Cb = C + z * sC + (size_t)blockIdx.y * 128 * ldc + (size_t)blockIdx.x * 128;
  if (MODE == 0) {
#pragma unroll
    for (int i = 0; i < 4; i++)
#pragma unroll
      for (int j = 0; j < 4; j++)
#pragma unroll
        for (int r = 0; r < 4; r++) {
          int row = wm * 64 + i * 16 + quad * 4 + r;
          int col = wn * 64 + j * 16 + lrow;
          Cb[(size_t)row * ldc + col] = f2bf(acc[i][j][r] * cscale);
        }
  } else {
    float* Lb = Lrow + z * NN + (size_t)blockIdx.y * 128;
#pragma unroll
    for (int i = 0; i < 4; i++)
#pragma unroll
      for (int r = 0; r < 4; r++) {
        int row = wm * 64 + i * 16 + quad * 4 + r;
        float rs = 0.f;
#pragma unroll
        for (int j = 0; j < 4; j++) {
          int col = wn * 64 + j * 16 + lrow;
          float e = __expf(fminf(acc[i][j][r] * cscale, 10.f));
          Cb[(size_t)row * ldc + col] = f2h(e);
          rs += e;
        }
        rs += __shfl_xor(rs, 1); rs += __shfl_xor(rs, 2);
        rs += __shfl_xor(rs, 4); rs += __shfl_xor(rs, 8);
        if (lrow == 0) atomicAdd(&Lb[row], rs);
      }
  }
}

// ===========================================================================
// 256x256 8-phase GEMM (T2 swizzle + T3/T4 counted vmcnt + T5 setprio).
// No T1 grid swizzle (r5 refuted). Plain cached direct stores (r4/r7
// refuted alternatives). NON-persistent (r9/r11 refuted). Grid (8,8,z):
// dispatcher generations = 4-batch/16MB L2-resident cohorts.
// MODE 0: store bf16(C*cscale). MODE 1: store fp16(exp(min(C,10))) + row
// expsum atomicAdd into Lrow.
// ===========================================================================
__device__ __forceinline__ void stage_half(const u16* __restrict__ g, int ld,
                                           int row0, int k0,
                                           u16* __restrict__ l, int tid) {
  int r  = tid >> 3;                    // 0..63
  int Lc = (tid & 7) ^ (r & 7);         // inverse-swizzled source chunk
  async16(g + (size_t)(row0 + r) * ld + k0 + Lc * 8, l + tid * 8);
  async16(g + (size_t)(row0 + 64 + r) * ld + k0 + Lc * 8, l + 4096 + tid * 8);
}

__device__ __forceinline__ bf16x8 ldf(const u16* __restrict__ h, int rbase,
                                      int lrow, int quad, int ks) {
  int rr = rbase + lrow;
  int pc = (ks * 4 + quad) ^ (lrow & 7);  // swizzled read chunk
  return *(const bf16x8*)&h[rr * 64 + pc * 8];
}

#define BAR() __builtin_amdgcn_s_barrier()
#define WAIT_LGKM()                                          \
  do {                                                       \
    asm volatile("s_waitcnt lgkmcnt(0)" ::: "memory");       \
    __builtin_amdgcn_sched_barrier(0);                       \
  } while (0)

#define READ_A(p, mh)                                                        \
  _Pragma("unroll") for (int i2 = 0; i2 < 4; ++i2)                           \
  _Pragma("unroll") for (int ks = 0; ks < 2; ++ks)                           \
      af[i2][ks] = ldf(sm + (p) * 32768 + wm * 8192, ((mh)*4 + i2) * 16,     \
                       lrow, quad, ks);

#define READ_B(p, nh)                                                        \
  _Pragma("unroll") for (int j2 = 0; j2 < 2; ++j2)                           \
  _Pragma("unroll") for (int ks = 0; ks < 2; ++ks)                           \
      bq[(nh)*2 + j2][ks] =                                                  \
          ldf(sm + (p) * 32768 + 16384 + (wn >> 1) * 8192,                   \
              (wn & 1) * 64 + ((nh)*2 + j2) * 16, lrow, quad, ks);

#define MFMA_Q(mh, nh)                                                       \
  __builtin_amdgcn_s_setprio(1);                                             \
  _Pragma("unroll") for (int i2 = 0; i2 < 4; ++i2)                           \
  _Pragma("unroll") for (int j2 = 0; j2 < 2; ++j2)                           \
  _Pragma("unroll") for (int ks = 0; ks < 2; ++ks)                           \
      acc[(mh)*4 + i2][(nh)*2 + j2] = __builtin_amdgcn_mfma_f32_16x16x32_bf16( \
          af[i2][ks], bq[(nh)*2 + j2][ks], acc[(mh)*4 + i2][(nh)*2 + j2],    \
          0, 0, 0);                                                          \
  __builtin_amdgcn_s_setprio(0);

#define STAGE_A(p, h, kt) \
  stage_half(Ab, lda, (h)*128, (kt)*64, sm + (p)*32768 + (h)*8192, tid)
#define STAGE_B(p, h, kt) \
  stage_half(Bb, ldb, (h)*128, (kt)*64, sm + (p)*32768 + 16384 + (h)*8192, tid)

template <int MODE>
__global__ __launch_bounds__(512, 2) void gemm256(
    const u16* __restrict__ A, const u16* __restrict__ B, u16* __restrict__ C,
    float* __restrict__ Lrow, int lda, int ldb, int ldc, int K,
    long long sA, long long sB, long long sC, float cscale) {
  const int tid  = threadIdx.x;
  const int wid  = tid >> 6, lane = tid & 63;
  const int wm   = wid >> 2, wn = wid & 3;   // 2 M-waves x 4 N-waves
  const int lrow = lane & 15, quad = lane >> 4;

  const int bxx = blockIdx.x;
  const int byy = blockIdx.y;
  const long long z = blockIdx.z;

  const u16* Ab = A + z * sA + (size_t)byy * 256 * lda;
  const u16* Bb = B + z * sB + (size_t)bxx * 256 * ldb;

  __shared__ __align__(16) u16 sm[65536];   // 128 KiB

  f32x4 acc[8][4];
#pragma unroll
  for (int i = 0; i < 8; i++)
#pragma unroll
    for (int j = 0; j < 4; j++) acc[i][j] = (f32x4){0.f, 0.f, 0.f, 0.f};

  bf16x8 af[4][2];   // current A m-half frags (4 mfrags x 2 ksteps)
  bf16x8 bq[4][2];   // current B tile frags  (4 nfrags x 2 ksteps)

  const int NITER = K >> 7;   // K/128 tile-pairs (K=512 -> 4)

  // ---- prologue: A0(0), B0(0), B1(1); allow B1(1) in flight
  STAGE_A(0, 0, 0); STAGE_A(0, 1, 0);
  STAGE_B(0, 0, 0); STAGE_B(0, 1, 0);
  STAGE_B(1, 0, 1); STAGE_B(1, 1, 1);
  asm volatile("s_waitcnt vmcnt(4)" ::: "memory");
  __builtin_amdgcn_sched_barrier(0);
  BAR();

  for (int it = 0; it < NITER; ++it) {
    const int t = 2 * it;
    const bool more = (it + 1 < NITER);

    // -- g1: tile t (p0), quadrant (mh0,nh0); stage A1h0(t+1)
    READ_A(0, 0); READ_B(0, 0);
    STAGE_A(1, 0, t + 1);
    BAR(); WAIT_LGKM();
    MFMA_Q(0, 0);
    BAR();
    // -- g2: (mh0,nh1); stage A1h1(t+1)
    READ_B(0, 1);
    STAGE_A(1, 1, t + 1);
    BAR(); WAIT_LGKM();
    MFMA_Q(0, 1);
    BAR();
    // -- g3: (mh1,nh0); stage B0h0(t+2)
    READ_A(0, 1);
    if (more) STAGE_B(0, 0, t + 2);
    BAR(); WAIT_LGKM();
    MFMA_Q(1, 0);
    BAR();
    // -- g4: (mh1,nh1); stage B0h1(t+2); counted vmcnt
    if (more) STAGE_B(0, 1, t + 2);
    BAR();
    MFMA_Q(1, 1);
    if (more) { asm volatile("s_waitcnt vmcnt(4)" ::: "memory"); }
    else      { asm volatile("s_waitcnt vmcnt(0)" ::: "memory"); }
    __builtin_amdgcn_sched_barrier(0);
    BAR();
    // -- g5: tile t+1 (p1), (mh0,nh0); stage A0h0(t+2)
    READ_A(1, 0); READ_B(1, 0);
    if (more) STAGE_A(0, 0, t + 2);
    BAR(); WAIT_LGKM();
    MFMA_Q(0, 0);
    BAR();
    // -- g6: (mh0,nh1); stage A0h1(t+2)
    READ_B(1, 1);
    if (more) STAGE_A(0, 1, t + 2);
    BAR(); WAIT_LGKM();
    MFMA_Q(0, 1);
    BAR();
    // -- g7: (mh1,nh0); stage B1h0(t+3)
    READ_A(1, 1);
    if (more) STAGE_B(1, 0, t + 3);
    BAR(); WAIT_LGKM();
    MFMA_Q(1, 0);
    BAR();
    // -- g8: (mh1,nh1); stage B1h1(t+3); counted vmcnt
    if (more) STAGE_B(1, 1, t + 3);
    BAR();
    MFMA_Q(1, 1);
    if (more) {
      asm volatile("s_waitcnt vmcnt(4)" ::: "memory");
      __builtin_amdgcn_sched_barrier(0);
    }
    BAR();
  }

  // ---- epilogue (direct cached stores). D col=lane&15, row=quad*4+reg
  u16* Cb = C + z * sC +
            (size_t)(byy * 256 + wm * 128) * ldc +
            (size_t)bxx * 256 + wn * 64;
  if (MODE == 0) {
#pragma unroll
    for (int i = 0; i < 8; i++)
#pragma unroll
      for (int j = 0; j < 4; j++)
#pragma unroll
        for (int r = 0; r < 4; r++) {
          int row = i * 16 + quad * 4 + r;
          int col = j * 16 + lrow;
          Cb[(size_t)row * ldc + col] = f2bf(acc[i][j][r] * cscale);
        }
  } else {
    float* Lb = Lrow + z * NN + (size_t)byy * 256 + wm * 128;
#pragma unroll
    for (int i = 0; i < 8; i++)
#pragma unroll
      for (int r = 0; r < 4; r++) {
        int row = i * 16 + quad * 4 + r;
        float rs = 0.f;
#pragma unroll
        for (int j = 0; j < 4; j++) {
          int col = j * 16 + lrow;
          float e = __expf(fminf(acc[i][j][r] * cscale, 10.f));
          Cb[(size_t)row * ldc + col] = f2h(e);
          rs += e;
        }
        rs += __shfl_xor(rs, 1); rs += __shfl_xor(rs, 2);
        rs += __shfl_xor(rs, 4); rs += __shfl_xor(rs, 8);
        if (lrow == 0) atomicAdd(&Lb[row], rs);
      }
  }
}

// ---------------------------------------------------------------------------
// fp32 -> bf16 cast for BOTH x (blocks [0,8192)) and Wq (blocks [8192,8320)).
// ---------------------------------------------------------------------------
__global__ void cast_two(const float* __restrict__ x, u16* __restrict__ xb,
                         const float* __restrict__ w, u16* __restrict__ wb) {
  int bid = blockIdx.x;
  const float* src;
  u16* dst;
  size_t i;
  if (bid < 8192) {
    src = x;  dst = xb; i = ((size_t)bid * 256 + threadIdx.x) * 8;
  } else {
    src = w;  dst = wb; i = ((size_t)(bid - 8192) * 256 + threadIdx.x) * 8;
  }
  float4 f0 = *(const float4*)(src + i);
  float4 f1 = *(const float4*)(src + i + 4);
  u16x8 r;
  r[0] = f2bf(f0.x); r[1] = f2bf(f0.y); r[2] = f2bf(f0.z); r[3] = f2bf(f0.w);
  r[4] = f2bf(f1.x); r[5] = f2bf(f1.y); r[6] = f2bf(f1.z); r[7] = f2bf(f1.w);
  *(u16x8*)(dst + i) = r;
}

// ---------------------------------------------------------------------------
// c[z*NN+m] += sum_n E[z][n0+n][m] / L[z*NN+n0+n]     (E already exp'ed)
// grid (n-chunks of 128, z), 256 thr, 8 cols/thread (16B/lane loads, G13).
// ---------------------------------------------------------------------------
__global__ void col_sum(const __half* __restrict__ E, const float* __restrict__ L,
                        float* __restrict__ c) {
  int m8 = threadIdx.x * 8;              // 256 thr x 8 = 2048 cols
  int n0 = blockIdx.x * 128;
  int z  = blockIdx.y;
  const u16* Ep = (const u16*)E + ((size_t)z * NN + n0) * NN + m8;
  const float* lp = L + (size_t)z * NN + n0;
  float a[8] = {0.f, 0.f, 0.f, 0.f, 0.f, 0.f, 0.f, 0.f};
#pragma unroll 2
  for (int n = 0; n < 128; n++) {
    u16x8 h = *(const u16x8*)&Ep[(size_t)n * NN];
    float il = 1.0f / lp[n];
#pragma unroll
    for (int j = 0; j < 8; j++) a[j] += h2f(h[j]) * il;
  }
  float* cb = c + (size_t)z * NN + m8;
#pragma unroll
  for (int j = 0; j < 8; j++) atomicAdd(&cb[j], a[j]);
}

// ---------------------------------------------------------------------------
// t[b][d] += sum_m c[b][m] * xb[b][m][d]
// grid (B, 16 m-chunks of 128), 256 thr = 64 d-groups x 4 m-groups;
// u16x8 loads (16B/lane), LDS partial-reduce, 512 atomics/block.
// ---------------------------------------------------------------------------
__global__ void tx_accum(const u16* __restrict__ xb, const float* __restrict__ c,
                         float* __restrict__ t) {
  int b = blockIdx.x, mc = blockIdx.y;
  int dgrp = threadIdx.x & 63;           // 64 x 8 = 512 d
  int mgrp = threadIdx.x >> 6;           // 4 x 32 = 128 m
  int d8 = dgrp * 8;
  const u16* vp = xb + ((size_t)b * NN + mc * 128 + mgrp * 32) * ND;
  const float* cp = c + b * NN + mc * 128 + mgrp * 32;
  float a[8] = {0.f, 0.f, 0.f, 0.f, 0.f, 0.f, 0.f, 0.f};
#pragma unroll 2
  for (int m = 0; m < 32; m++) {
    float cm = cp[m];
    u16x8 v = *(const u16x8*)&vp[(size_t)m * ND + d8];
#pragma unroll
    for (int j = 0; j < 8; j++) a[j] += cm * bf2f(v[j]);
  }
  __shared__ float smr[4][512];
#pragma unroll
  for (int j = 0; j < 8; j++) smr[mgrp][d8 + j] = a[j];
  __syncthreads();
  if (mgrp == 0) {
    float* tb = t + b * ND + d8;
#pragma unroll
    for (int j = 0; j < 8; j++)
      atomicAdd(&tb[j], a[j] + smr[1][d8 + j] + smr[2][d8 + j] + smr[3][d8 + j]);
  }
}

// ---------------------------------------------------------------------------
// out[b][d] = (1/NN) * sum_l t[b][l] * Wv[l][d]   (Wv fp32, full precision)
// grid (B, 8 d-chunks of 64), 256 thr = 64 d x 4 l-groups, LDS reduce.
// ---------------------------------------------------------------------------
__global__ void final_wv(const float* __restrict__ t, const float* __restrict__ Wv,
                         float* __restrict__ out) {
  int b = blockIdx.x;
  int d = blockIdx.y * 64 + (threadIdx.x & 63);
  int lgrp = threadIdx.x >> 6;           // 4 x 128 = 512 l
  const float* tb = t + b * ND + lgrp * 128;
  const float* wp = Wv + (size_t)lgrp * 128 * ND + d;
  float a = 0.f;
#pragma unroll 4
  for (int l = 0; l < 128; l++) a += tb[l] * wp[(size_t)l * ND];
  __shared__ float smr[4][64];
  smr[lgrp][threadIdx.x & 63] = a;
  __syncthreads();
  if (lgrp == 0)
    out[b * ND + d] = (a + smr[1][threadIdx.x & 63] + smr[2][threadIdx.x & 63] +
                       smr[3][threadIdx.x & 63]) * (1.f / (float)NN);
}

// ---------------------------------------------------------------------------
extern "C" void kernel_launch(void* const* d_in, const int* in_sizes, int n_in,
                              void* d_out, int out_size, void* d_ws, size_t ws_size,
                              hipStream_t stream) {
  const float* x  = (const float*)d_in[0];  // [16,2048,512] fp32
  const float* Wk = (const float*)d_in[1];  // [512,512]     fp32
  const float* Wq = (const float*)d_in[2];  // [512,512]     fp32
  const float* Wv = (const float*)d_in[3];  // [512,512]     fp32
  float* out = (float*)d_out;               // [16,512]      fp32

  // --- small fixed region (~1.3 MB). L,c,t contiguous (one memset). ---
  char* ws = (char*)d_ws;
  size_t off = 0;
  float* L   = (float*)(ws + off); off += (size_t)NB * NN * 4;     // 128 KB
  float* c   = (float*)(ws + off); off += (size_t)NB * NN * 4;     // 128 KB
  float* t   = (float*)(ws + off); off += (size_t)NB * ND * 4;     // 32 KB
  u16* Wqb   = (u16*)(ws + off);   off += (size_t)ND * ND * 2;     // 512 KB
  u16* Mt    = (u16*)(ws + off);   off += (size_t)ND * ND * 2;     // 512 KB
  const size_t small_total = off;

  // --- big region: xb (33.6) + y (33.6) + E chunk (adaptive) ---
  const size_t XBSZ = (size_t)NB * NN * ND * 2;   // 33.55 MB
  const size_t SB1  = (size_t)NN * NN * 2;        // 8.39 MB / batch of E
  u16* xb   = (u16*)(ws + small_total);
  u16* y    = (u16*)(ws + small_total + XBSZ);
  __half* E = (__half*)(ws + small_total + 2 * XBSZ);
  size_t srem = ws_size > small_total + 2 * XBSZ
              ? ws_size - small_total - 2 * XBSZ : 0;
  int chb = 0, sr = 128;
  if      (srem >= 16 * SB1) chb = 16;
  else if (srem >=  8 * SB1) chb = 8;
  else if (srem >=  4 * SB1) chb = 4;
  else if (srem >=  2 * SB1) chb = 2;
  else if (srem >=  1 * SB1) chb = 1;
  else {
    if      (srem >= (size_t)1024 * NN * 2) sr = 1024;
    else if (srem >= (size_t)512  * NN * 2) sr = 512;
    else if (srem >= (size_t)256  * NN * 2) sr = 256;
  }

  hipMemsetAsync(L, 0, (size_t)(2 * NB * NN + NB * ND) * sizeof(float), stream);

  // xb = bf16(x) and Wqb = bf16(Wq) in one launch
  cast_two<<<8320, 256, 0, stream>>>(x, xb, Wq, Wqb);

  // Mt[n][k] = SSCALE * sum_l Wk[n][l]*Wq[k][l]  (tiny — 128² kernel)
  gemm_bt<0, true><<<dim3(4, 4, 1), 256, 0, stream>>>(
      Wk, Wqb, Mt, nullptr, ND, ND, ND, ND, 0, 0, 0, SSCALE);

  // y = x * M   (M=32768, N=512, K=512) -> bf16, 256² 8-phase kernel
  gemm256<0><<<dim3(2, 128, 1), 512, 0, stream>>>(
      xb, Mt, y, nullptr, ND, ND, ND, ND, 0, 0, 0, 1.0f);

  const long long sR = (long long)NN * ND;   // per-batch row stride (y, xb)
  const long long sS = (long long)NN * NN;

  if (chb >= 1) {
    for (int cc = 0; cc < NB / chb; ++cc) {
      size_t o = (size_t)cc * chb * NN;
      // E = exp(y_b * xb_b^T), row sums into L
      gemm256<1><<<dim3(8, 8, chb), 512, 0, stream>>>(
          y + o * ND, xb + o * ND, (u16*)E, L + o, ND, ND, NN, ND,
          sR, sR, sS, 1.0f);
      col_sum<<<dim3(16, chb), 256, 0, stream>>>(E, L + o, c + o);
    }
  } else if (sr >= 256) {  // sub-batch chunks of sr rows, 256² kernel
    for (int b = 0; b < NB; ++b) {
      for (int ch = 0; ch < NN / sr; ++ch) {
        size_t o = (size_t)b * NN + (size_t)ch * sr;
        gemm256<1><<<dim3(8, sr / 256, 1), 512, 0, stream>>>(
            y + o * ND, xb + (size_t)b * NN * ND, (u16*)E, L + o,
            ND, ND, NN, ND, 0, 0, 0, 1.0f);
        col_sum<<<dim3(sr / 128, 1), 256, 0, stream>>>(E, L + o, c + b * NN);
      }
    }
  } else {  // tiny workspace fallback: old 128² kernel
    for (int b = 0; b < NB; ++b) {
      for (int ch = 0; ch < NN / sr; ++ch) {
        size_t o = (size_t)b * NN + (size_t)ch * sr;
        gemm_bt<1, false><<<dim3(16, sr / 128, 1), 256, 0, stream>>>(
            y + o * ND, xb + (size_t)b * NN * ND, (u16*)E, L + o,
            ND, ND, NN, ND, 0, 0, 0, 1.0f);
        col_sum<<<dim3(sr / 128, 1), 256, 0, stream>>>(E, L + o, c + b * NN);
      }
    }
  }

  // t[b] = c_b^T x_b ;  out = (t * Wv) / NN
  tx_accum<<<dim3(NB, 16), 256, 0, stream>>>(xb, c, t);
  final_wv<<<dim3(NB, 8), 256, 0, stream>>>(t, Wv, out);
  (void)in_sizes; (void)n_in; (void)out_size;
}